// Round 3
// baseline (225.472 us; speedup 1.0000x reference)
//
#include <hip/hip_runtime.h>
#include <hip/hip_bf16.h>

#define B_N     2048
#define IN_N    512
#define SEQ_N   128
#define HID_N   12
#define HP_N    16
#define OUT_N   3
#define CST     524   // C row stride in floats: bank = (3h + r) % 32, <=2-way

typedef __attribute__((ext_vector_type(8))) short short8;
typedef __attribute__((ext_vector_type(4))) float f32x4;
typedef unsigned int uint;
typedef unsigned short ushort;

__device__ __forceinline__ float fast_tanh(float x) {
    float e = __builtin_amdgcn_exp2f(x * 2.8853900817779268f);
    return 1.0f - 2.0f * __builtin_amdgcn_rcpf(e + 1.0f);
}

__device__ __forceinline__ ushort f2bf(float f) {   // RNE fp32->bf16
    uint u = __float_as_uint(f);
    u += 0x7fffu + ((u >> 16) & 1u);
    return (ushort)(u >> 16);
}

__device__ __forceinline__ float bf2f(ushort s) {
    return __uint_as_float(((uint)s) << 16);
}

// ---------------------------------------------------------------------------
// k_prep: pack embT = emb^T (128 s x 512 r) into MFMA A-fragment order.
// Frag f = tile*16 + ks covers s in [tile*16,+16), r in [ks*32,+32).
// Lane l holds A[m=l&15][k=(l>>4)*8+j] = emb[r0+j][s], packed bf16x8 (uint4).
// embF total = 128 frags * 1 KB = 128 KB, L1/L2-resident in k_pre.
// ---------------------------------------------------------------------------
__global__ __launch_bounds__(64) void k_prep(
    const float* __restrict__ emb, ushort* __restrict__ embF)
{
    const int f  = blockIdx.x;          // 0..127
    const int l  = threadIdx.x;
    const int t8 = f >> 4, ks = f & 15;
    const int s  = t8 * 16 + (l & 15);
    const int r0 = ks * 32 + (l >> 4) * 8;
    ushort v[8];
    #pragma unroll
    for (int j = 0; j < 8; ++j)
        v[j] = f2bf(emb[(r0 + j) * SEQ_N + s]);
    uint4 o;
    o.x = (uint)v[0] | ((uint)v[1] << 16);
    o.y = (uint)v[2] | ((uint)v[3] << 16);
    o.z = (uint)v[4] | ((uint)v[5] << 16);
    o.w = (uint)v[6] | ((uint)v[7] << 16);
    ((uint4*)embF)[f * 64 + l] = o;
}

// ---------------------------------------------------------------------------
// k_pre v3: pre[b] = embT(128x512) @ C_b(512x16) via scatter-built C_b.
//   C_b[h][r] = sum_{i: x[b,i]=r} w_ih_f[h,i]   (LDS float atomics)
// Then 8 s-tiles x 16 K-steps of mfma_f32_16x16x32_bf16 with A straight
// from prepacked global embF (coalesced, cache-resident). No barriers:
// each wave owns a private C buffer and 2 sequential batches.
// ---------------------------------------------------------------------------
__global__ __launch_bounds__(128) void k_pre(
    const int* __restrict__ x, const ushort* __restrict__ embF,
    const float* __restrict__ w_ih_f, ushort* __restrict__ preB)
{
    __shared__ __align__(16) float Csh[2][12 * CST];   // 50.3 KB

    const int t    = threadIdx.x;
    const int w    = t >> 6;
    const int l    = t & 63;
    const int h16  = l & 15;
    const int quad = l >> 4;
    float* Cw = Csh[w];

    for (int bi = 0; bi < 2; ++bi) {
        const int b = blockIdx.x * 4 + w * 2 + bi;

        // zero C (wave-private, in-order with following ds ops)
        float4 z4 = make_float4(0.f, 0.f, 0.f, 0.f);
        for (int idx = l; idx < (12 * CST) / 4; idx += 64)
            ((float4*)Cw)[idx] = z4;

        // scatter-add: C[h][x[b,i]] += w[h][i]
        #pragma unroll
        for (int k = 0; k < 8; ++k) {
            int i = k * 64 + l;
            int r = x[b * IN_N + i];
            #pragma unroll
            for (int h = 0; h < 12; ++h)
                atomicAdd(&Cw[h * CST + r], w_ih_f[h * IN_N + i]);
        }

        // B-fragments: lane h16 reads C[h16][ks*32 + quad*8 .. +7] -> bf16x8
        short8 bf[16];
        #pragma unroll
        for (int ks = 0; ks < 16; ++ks) {
            short8 v = {0, 0, 0, 0, 0, 0, 0, 0};
            if (h16 < 12) {
                const float* cp = Cw + h16 * CST + ks * 32 + quad * 8;
                float4 c0 = *(const float4*)cp;
                float4 c1 = *(const float4*)(cp + 4);
                v[0] = (short)f2bf(c0.x); v[1] = (short)f2bf(c0.y);
                v[2] = (short)f2bf(c0.z); v[3] = (short)f2bf(c0.w);
                v[4] = (short)f2bf(c1.x); v[5] = (short)f2bf(c1.y);
                v[6] = (short)f2bf(c1.z); v[7] = (short)f2bf(c1.w);
            }
            bf[ks] = v;
        }

        // MFMA: A-frags straight from global embF (16B/lane coalesced)
        const uint4* eF = (const uint4*)embF;
        #pragma unroll
        for (int t8 = 0; t8 < 8; ++t8) {
            f32x4 acc = {0.f, 0.f, 0.f, 0.f};
            #pragma unroll
            for (int ks = 0; ks < 16; ++ks) {
                union { uint4 u; short8 s; } cv;
                cv.u = eF[(t8 * 16 + ks) * 64 + l];
                acc = __builtin_amdgcn_mfma_f32_16x16x32_bf16(cv.s, bf[ks], acc, 0, 0, 0);
            }
            // D: col = h16, row = quad*4 + reg  (s within tile)
            ushort* pb = preB + ((size_t)b * SEQ_N + t8 * 16 + quad * 4) * HP_N + h16;
            pb[0]        = f2bf(acc[0]);
            pb[HP_N]     = f2bf(acc[1]);
            pb[2 * HP_N] = f2bf(acc[2]);
            pb[3 * HP_N] = f2bf(acc[3]);
        }
    }
}

// ---------------------------------------------------------------------------
// k_rev: rev[b][h] = tanh( sum_i emb[x[b,i],127]*w_ih_r[h,i] + b_ih_r + b_hh_r )
// ---------------------------------------------------------------------------
__global__ __launch_bounds__(256) void k_rev(
    const int* __restrict__ x, const float* __restrict__ emb,
    const float* __restrict__ w_ih_r,
    const float* __restrict__ b_ih_r, const float* __restrict__ b_hh_r,
    float* __restrict__ rev)
{
    const int b = blockIdx.x * 4 + (threadIdx.x >> 6);
    const int l = threadIdx.x & 63;

    float p[12];
    #pragma unroll
    for (int h = 0; h < 12; ++h) p[h] = 0.f;

    for (int k = 0; k < 8; ++k) {
        int i = l + k * 64;
        int r = x[b * IN_N + i];
        float ev = emb[r * SEQ_N + 127];
        #pragma unroll
        for (int h = 0; h < 12; ++h) p[h] += ev * w_ih_r[h * IN_N + i];
    }
    #pragma unroll
    for (int off = 32; off; off >>= 1) {
        #pragma unroll
        for (int h = 0; h < 12; ++h) p[h] += __shfl_xor(p[h], off);
    }
    if (l == 0) {
        #pragma unroll
        for (int h = 0; h < 12; ++h)
            rev[b * HP_N + h] = fast_tanh(p[h] + b_ih_r[h] + b_hh_r[h]);
        #pragma unroll
        for (int h = 12; h < 16; ++h) rev[b * HP_N + h] = 0.f;
    }
}

// ---------------------------------------------------------------------------
// k_rnn: 16 lanes per b (lane j owns hidden j), h broadcast via ds_bpermute.
// 64 thr = 4 b per block, 512 blocks (all CUs busy).
// ---------------------------------------------------------------------------
__global__ __launch_bounds__(64) void k_rnn(
    const ushort* __restrict__ preB, const float* __restrict__ rev,
    const float* __restrict__ w_hh_f,
    const float* __restrict__ b_ih_f, const float* __restrict__ b_hh_f,
    const float* __restrict__ fc_w, const float* __restrict__ fc_b,
    float* __restrict__ out)
{
    __shared__ float ho[4][40];

    const int tid = threadIdx.x;       // 0..63
    const int j   = tid & 15;
    const int jj  = (j < 12) ? j : 0;
    const int gid = tid >> 4;          // 0..3
    const int b   = blockIdx.x * 4 + gid;
    const int baseaddr = (tid & 48) << 2;

    const float4* wr = (const float4*)(w_hh_f + jj * 12);
    float4 w0 = wr[0], w1 = wr[1], w2 = wr[2];
    float W[12] = {w0.x, w0.y, w0.z, w0.w, w1.x, w1.y, w1.z, w1.w,
                   w2.x, w2.y, w2.z, w2.w};
    const float bias = b_ih_f[jj] + b_hh_f[jj];

    const ushort* pb = preB + (size_t)b * SEQ_N * HP_N + j;
    ushort pq[8];
    #pragma unroll
    for (int k = 0; k < 8; ++k) pq[k] = pb[k * HP_N];

    float h = 0.f;
    for (int s8 = 0; s8 < 16; ++s8) {
        #pragma unroll
        for (int k = 0; k < 8; ++k) {
            int s = s8 * 8 + k;
            float p = bf2f(pq[k]) + bias;
            pq[k] = pb[((s + 8) & 127) * HP_N];     // branchless prefetch
            int hb = __float_as_int(h);
            float hk[12];
            #pragma unroll
            for (int kk = 0; kk < 12; ++kk)
                hk[kk] = __int_as_float(__builtin_amdgcn_ds_bpermute(baseaddr + 4 * kk, hb));
            float c0 = p, c1 = 0.f, c2 = 0.f;
            #pragma unroll
            for (int u = 0; u < 4; ++u) {
                c0 = __builtin_fmaf(W[u],     hk[u],     c0);
                c1 = __builtin_fmaf(W[4 + u], hk[4 + u], c1);
                c2 = __builtin_fmaf(W[8 + u], hk[8 + u], c2);
            }
            h = fast_tanh(c0 + c1 + c2);
        }
    }

    // epilogue FC (intra-wave LDS, no barrier needed)
    ho[gid][j]      = h;
    ho[gid][20 + j] = rev[b * HP_N + j];
    if (j < OUT_N) {
        const float* fw = fc_w + j * 24;
        float o = fc_b[j];
        #pragma unroll
        for (int k = 0; k < 12; ++k)
            o += fw[k] * ho[gid][k] + fw[12 + k] * ho[gid][20 + k];
        out[b * OUT_N + j] = o;
    }
}

// ---------------------------------------------------------------------------
extern "C" void kernel_launch(void* const* d_in, const int* in_sizes, int n_in,
                              void* d_out, int out_size, void* d_ws, size_t ws_size,
                              hipStream_t stream) {
    const int*   x      = (const int*)  d_in[0];
    const float* emb    = (const float*)d_in[1];
    const float* w_ih_f = (const float*)d_in[2];
    const float* w_hh_f = (const float*)d_in[3];
    const float* b_ih_f = (const float*)d_in[4];
    const float* b_hh_f = (const float*)d_in[5];
    const float* w_ih_r = (const float*)d_in[6];
    const float* b_ih_r = (const float*)d_in[8];
    const float* b_hh_r = (const float*)d_in[9];
    const float* fc_w   = (const float*)d_in[10];
    const float* fc_b   = (const float*)d_in[11];
    float* out = (float*)d_out;

    ushort* preB = (ushort*)d_ws;                       // 8 MB
    float*  rev  = (float*)((char*)d_ws + 8388608);     // 128 KB
    ushort* embF = (ushort*)((char*)d_ws + 8519680);    // 128 KB

    k_prep<<<128,    64, 0, stream>>>(emb, embF);
    k_pre <<<B_N/4, 128, 0, stream>>>(x, embF, w_ih_f, preB);
    k_rev <<<B_N/4, 256, 0, stream>>>(x, emb, w_ih_r, b_ih_r, b_hh_r, rev);
    k_rnn <<<B_N/4,  64, 0, stream>>>(preB, rev, w_hh_f, b_ih_f, b_hh_f, fc_w, fc_b, out);
}

// Round 4
// 175.847 us; speedup vs baseline: 1.2822x; 1.2822x over previous
//
#include <hip/hip_runtime.h>
#include <hip/hip_bf16.h>

#define B_N     2048
#define IN_N    512
#define SEQ_N   128
#define HID_N   12
#define HP_N    16
#define OUT_N   3
#define CSTF    524   // C f32 row stride: h*524%32 spreads banks, 2-way max
#define CSTB    520   // C bf16 row stride (ushorts): 1040B, 16B-aligned rows,
                      // per-row dword shift 260%32=4 -> 2-way banks (free)

typedef __attribute__((ext_vector_type(8))) short short8;
typedef __attribute__((ext_vector_type(4))) float f32x4;
typedef unsigned int uint;
typedef unsigned short ushort;

__device__ __forceinline__ float fast_tanh(float x) {
    float e = __builtin_amdgcn_exp2f(x * 2.8853900817779268f);
    return 1.0f - 2.0f * __builtin_amdgcn_rcpf(e + 1.0f);
}

__device__ __forceinline__ ushort f2bf(float f) {   // RNE fp32->bf16
    uint u = __float_as_uint(f);
    u += 0x7fffu + ((u >> 16) & 1u);
    return (ushort)(u >> 16);
}

// ---------------------------------------------------------------------------
// k_prep: pack embT (128 s x 512 r) into MFMA A-fragment order (bf16).
// Frag f = t8*16 + ks covers s in [t8*16,+16), r in [ks*32,+32).
// Lane l holds A[m=l&15][k=(l>>4)*8+j] = emb[r0+j][s], uint4-packed.
// ---------------------------------------------------------------------------
__global__ __launch_bounds__(64) void k_prep(
    const float* __restrict__ emb, ushort* __restrict__ embF)
{
    const int f  = blockIdx.x;          // 0..127
    const int l  = threadIdx.x;
    const int t8 = f >> 4, ks = f & 15;
    const int s  = t8 * 16 + (l & 15);
    const int r0 = ks * 32 + (l >> 4) * 8;
    ushort v[8];
    #pragma unroll
    for (int j = 0; j < 8; ++j)
        v[j] = f2bf(emb[(r0 + j) * SEQ_N + s]);
    uint4 o;
    o.x = (uint)v[0] | ((uint)v[1] << 16);
    o.y = (uint)v[2] | ((uint)v[3] << 16);
    o.z = (uint)v[4] | ((uint)v[5] << 16);
    o.w = (uint)v[6] | ((uint)v[7] << 16);
    ((uint4*)embF)[f * 64 + l] = o;
}

// ---------------------------------------------------------------------------
// k_pre v4: one block (256 thr) per batch.
//   C_b[h][r] = sum_{i: x[b,i]=r} w_ih_f[h,i]      (LDS f32 atomics)
//   preB[b][h][s] = (embT @ C_b)[s][h]             (mfma 16x16x32 bf16)
// C converted to bf16 in-place (regs + barrier); B-frags via ds_read_b128;
// A-frags stream from prepacked global embF (L2-resident, 16B/lane).
// Output packed 4xbf16 -> uint2 stores (full sectors, no RMW).
// ---------------------------------------------------------------------------
__global__ __launch_bounds__(256) void k_pre(
    const int* __restrict__ x, const ushort* __restrict__ embF,
    const float* __restrict__ w_ih_f, ushort* __restrict__ preB)
{
    __shared__ __align__(16) float U[12 * CSTF];   // 25.2 KB; reused for Cb
    __shared__ int xb[IN_N];
    ushort* Cb = (ushort*)U;                       // 16*CSTB ushorts = 16.6 KB

    const int t = threadIdx.x;
    const int b = blockIdx.x;

    ((int2*)xb)[t] = ((const int2*)(x + b * IN_N))[t];
    float4 z4 = make_float4(0.f, 0.f, 0.f, 0.f);
    for (int idx = t; idx < (12 * CSTF) / 4; idx += 256)
        ((float4*)U)[idx] = z4;
    __syncthreads();

    // scatter: C[h][x[b,i]] += w[h][i]
    #pragma unroll
    for (int k = 0; k < 2; ++k) {
        int i = t + k * 256;
        int r = xb[i];
        #pragma unroll
        for (int h = 0; h < 12; ++h)
            atomicAdd(&U[h * CSTF + r], w_ih_f[h * IN_N + i]);
    }
    __syncthreads();

    // convert f32 C -> bf16 Cb in place: read to regs, barrier, write
    float tmp[24];
    #pragma unroll
    for (int h = 0; h < 12; ++h) {
        tmp[2 * h]     = U[h * CSTF + t];
        tmp[2 * h + 1] = U[h * CSTF + 256 + t];
    }
    __syncthreads();
    #pragma unroll
    for (int h = 0; h < 12; ++h) {
        Cb[h * CSTB + t]       = f2bf(tmp[2 * h]);
        Cb[h * CSTB + 256 + t] = f2bf(tmp[2 * h + 1]);
    }
    __syncthreads();
    // NOTE: Cb rows 12..15 are stale garbage; they only feed MFMA output
    // columns n>=12 which are never stored (columns are independent).

    const int w    = t >> 6;
    const int l    = t & 63;
    const int h16  = l & 15;
    const int quad = l >> 4;
    const uint4* eF = (const uint4*)embF;

    #pragma unroll
    for (int tt = 0; tt < 2; ++tt) {
        const int t8 = w * 2 + tt;
        f32x4 acc = {0.f, 0.f, 0.f, 0.f};
        #pragma unroll
        for (int ks = 0; ks < 16; ++ks) {
            union { uint4 u; short8 s; } av, bv;
            av.u = eF[(t8 * 16 + ks) * 64 + l];
            bv.u = *(const uint4*)&Cb[h16 * CSTB + ks * 32 + quad * 8];
            acc = __builtin_amdgcn_mfma_f32_16x16x32_bf16(av.s, bv.s, acc, 0, 0, 0);
        }
        // D: col=h16, row=quad*4+reg (s in tile). Write [b][h][s], 8B/lane.
        if (h16 < HID_N) {
            uint2 o;
            o.x = (uint)f2bf(acc[0]) | ((uint)f2bf(acc[1]) << 16);
            o.y = (uint)f2bf(acc[2]) | ((uint)f2bf(acc[3]) << 16);
            *(uint2*)(preB + (size_t)b * (HP_N * SEQ_N) + h16 * SEQ_N
                      + t8 * 16 + quad * 4) = o;
        }
    }
}

// ---------------------------------------------------------------------------
// k_scan: fused reverse-step + 128-step forward scan + FC.
// 64 thr = 1 wave = 4 batches; 16 lanes per batch, lane j owns hidden j.
// pre rows vec-loaded (uint4, [b][h][s] layout); h exchange via ds_bpermute.
// ---------------------------------------------------------------------------
__global__ __launch_bounds__(64) void k_scan(
    const ushort* __restrict__ preB,
    const int* __restrict__ x, const float* __restrict__ emb,
    const float* __restrict__ w_ih_r,
    const float* __restrict__ b_ih_r, const float* __restrict__ b_hh_r,
    const float* __restrict__ w_hh_f,
    const float* __restrict__ b_ih_f, const float* __restrict__ b_hh_f,
    const float* __restrict__ fc_w, const float* __restrict__ fc_b,
    float* __restrict__ out)
{
    __shared__ float ho[4][40];

    const int tid = threadIdx.x;
    const int j   = tid & 15;
    const int jj  = (j < 12) ? j : 0;
    const int gid = tid >> 4;
    const int b   = blockIdx.x * 4 + gid;
    const int baseaddr = (tid & 48) << 2;

    // ---- reverse one-step RNN: lane j accumulates i = j + 16k over all h
    float pr[12];
    #pragma unroll
    for (int h = 0; h < 12; ++h) pr[h] = 0.f;
    for (int k = 0; k < 32; ++k) {
        int i = j + k * 16;
        int r = x[b * IN_N + i];
        float ev = emb[r * SEQ_N + 127];
        #pragma unroll
        for (int h = 0; h < 12; ++h)
            pr[h] = __builtin_fmaf(ev, w_ih_r[h * IN_N + i], pr[h]);
    }
    #pragma unroll
    for (int off = 1; off < 16; off <<= 1)
        #pragma unroll
        for (int h = 0; h < 12; ++h) pr[h] += __shfl_xor(pr[h], off);
    float prj = pr[0];
    #pragma unroll
    for (int h = 1; h < 12; ++h) prj = (jj == h) ? pr[h] : prj;
    const float hrev = fast_tanh(prj + b_ih_r[jj] + b_hh_r[jj]);

    // ---- forward scan
    const float4* wr = (const float4*)(w_hh_f + jj * 12);
    float4 w0 = wr[0], w1 = wr[1], w2 = wr[2];
    float W[12] = {w0.x, w0.y, w0.z, w0.w, w1.x, w1.y, w1.z, w1.w,
                   w2.x, w2.y, w2.z, w2.w};
    const float bias = b_ih_f[jj] + b_hh_f[jj];

    const uint4* pb = (const uint4*)(preB + (size_t)b * (HP_N * SEQ_N) + j * SEQ_N);
    uint4 cur = pb[0];
    uint4 nxt = pb[1];

    float h = 0.f;
    for (int s8 = 0; s8 < 16; ++s8) {
        uint ww[4] = {cur.x, cur.y, cur.z, cur.w};
        cur = nxt;
        nxt = pb[(s8 + 2) & 15];            // branchless prefetch (wraps, harmless)
        #pragma unroll
        for (int k2 = 0; k2 < 4; ++k2) {
            uint u = ww[k2];
            #pragma unroll
            for (int half = 0; half < 2; ++half) {
                float p = half ? __uint_as_float(u & 0xffff0000u)
                               : __uint_as_float(u << 16);
                p += bias;
                int hb = __float_as_int(h);
                float a0 = p, a1 = 0.f, a2 = 0.f;
                #pragma unroll
                for (int kk = 0; kk < 4; ++kk) {
                    float h0 = __int_as_float(__builtin_amdgcn_ds_bpermute(baseaddr + 4 * kk, hb));
                    float h1 = __int_as_float(__builtin_amdgcn_ds_bpermute(baseaddr + 4 * (kk + 4), hb));
                    float h2 = __int_as_float(__builtin_amdgcn_ds_bpermute(baseaddr + 4 * (kk + 8), hb));
                    a0 = __builtin_fmaf(W[kk],     h0, a0);
                    a1 = __builtin_fmaf(W[kk + 4], h1, a1);
                    a2 = __builtin_fmaf(W[kk + 8], h2, a2);
                }
                h = fast_tanh(a0 + a1 + a2);
            }
        }
    }

    // ---- FC epilogue (intra-wave LDS, no barrier)
    ho[gid][j]      = h;
    ho[gid][20 + j] = hrev;
    if (j < OUT_N) {
        const float* fw = fc_w + j * 24;
        float o = fc_b[j];
        #pragma unroll
        for (int k = 0; k < 12; ++k)
            o += fw[k] * ho[gid][k] + fw[12 + k] * ho[gid][20 + k];
        out[b * OUT_N + j] = o;
    }
}

// ---------------------------------------------------------------------------
extern "C" void kernel_launch(void* const* d_in, const int* in_sizes, int n_in,
                              void* d_out, int out_size, void* d_ws, size_t ws_size,
                              hipStream_t stream) {
    const int*   x      = (const int*)  d_in[0];
    const float* emb    = (const float*)d_in[1];
    const float* w_ih_f = (const float*)d_in[2];
    const float* w_hh_f = (const float*)d_in[3];
    const float* b_ih_f = (const float*)d_in[4];
    const float* b_hh_f = (const float*)d_in[5];
    const float* w_ih_r = (const float*)d_in[6];
    const float* b_ih_r = (const float*)d_in[8];
    const float* b_hh_r = (const float*)d_in[9];
    const float* fc_w   = (const float*)d_in[10];
    const float* fc_b   = (const float*)d_in[11];
    float* out = (float*)d_out;

    ushort* preB = (ushort*)d_ws;                       // [2048][16][128] bf16 = 8 MB
    ushort* embF = (ushort*)((char*)d_ws + 8388608);    // 128 KB

    k_prep<<<128,     64, 0, stream>>>(emb, embF);
    k_pre <<<B_N,    256, 0, stream>>>(x, embF, w_ih_f, preB);
    k_scan<<<B_N / 4, 64, 0, stream>>>(preB, x, emb, w_ih_r, b_ih_r, b_hh_r,
                                       w_hh_f, b_ih_f, b_hh_f, fc_w, fc_b, out);
}